// Round 5
// baseline (107.795 us; speedup 1.0000x reference)
//
#include <hip/hip_runtime.h>

// B=16, C=4, H=512, W=512 ; rows=64 ; row length=262144 ; k=26214
// answer = sum(topk loss per row) / (64*26214)
//
// Single-pass selection: per-row linear histogram (2048 bins over [0,8), width 1/256)
// with per-bin count AND exact f32 sum. Top-k sum = exact sums of full bins above the
// threshold bin + rem1 * bin_center(threshold bin). Center approx error <= 1/512 per
// element, only for rem1 elements -> ~1e-4 on output vs 3.1e-2 threshold.

#define ROWS 64
#define ROW_N4 65536            // float4 per row
#define K_SEL 26214u
#define THREADS 256
#define BINS 2048
#define CHUNK4 2048             // float4 per block (8192 floats)

// fast BCE-with-logits: max(x,0) - x*y + log1p(exp(-|x|))
// log1p(e^-a) = ln2 * log2(1 + 2^(-a*log2e)) -> v_exp_f32 + v_log_f32
__device__ __forceinline__ float loss_fast(float x, float y) {
    float a = fabsf(x);
    float t = __builtin_amdgcn_exp2f(a * -1.44269504088896f);       // e^-a
    float sp = 0.69314718055995f * __builtin_amdgcn_logf(1.0f + t); // ln2*log2(1+t)
    return fmaxf(x, 0.0f) - x * y + sp;
}
__device__ __forceinline__ unsigned bin_of(float l) {
    unsigned b = (unsigned)(l * 256.0f);    // l >= 0 always
    return b > (BINS - 1u) ? (BINS - 1u) : b;
}

// ---------- Single data pass: per-row linear histogram (count + exact f32 sum) ----------
__global__ __launch_bounds__(THREADS)
void k_main(const float4* __restrict__ lg, const float4* __restrict__ tg,
            unsigned* __restrict__ gcnt, float* __restrict__ gsum) {
    __shared__ unsigned hc[BINS];   // 8 KB
    __shared__ float    hs[BINS];   // 8 KB
    int t = threadIdx.x;
    for (int i = t; i < BINS; i += THREADS) { hc[i] = 0; hs[i] = 0.0f; }
    __syncthreads();

    int row = blockIdx.x >> 5;
    int chunk = blockIdx.x & 31;
    int base = row * ROW_N4 + chunk * CHUNK4;

#pragma unroll
    for (int j = 0; j < 8; ++j) {
        int idx = base + j * THREADS + t;
        float4 x = lg[idx];
        float4 y = tg[idx];
        float l0 = loss_fast(x.x, y.x);
        float l1 = loss_fast(x.y, y.y);
        float l2 = loss_fast(x.z, y.z);
        float l3 = loss_fast(x.w, y.w);
        unsigned b0 = bin_of(l0), b1 = bin_of(l1), b2 = bin_of(l2), b3 = bin_of(l3);
        atomicAdd(&hc[b0], 1u); atomicAdd(&hs[b0], l0);
        atomicAdd(&hc[b1], 1u); atomicAdd(&hs[b1], l1);
        atomicAdd(&hc[b2], 1u); atomicAdd(&hs[b2], l2);
        atomicAdd(&hc[b3], 1u); atomicAdd(&hs[b3], l3);
    }
    __syncthreads();
    unsigned* gc = gcnt + row * BINS;
    float*    gs = gsum + row * BINS;
    for (int i = t; i < BINS; i += THREADS) {
        unsigned c = hc[i];
        if (c) { atomicAdd(&gc[i], c); atomicAdd(&gs[i], hs[i]); }
    }
}

// ---------- Per-row selection: find b1/rem1, total = exact sums above + rem1*center ----------
__global__ __launch_bounds__(THREADS)
void k_finalize(const unsigned* __restrict__ gcnt, const float* __restrict__ gsum,
                double* __restrict__ rowtot) {
    int row = blockIdx.x;
    int t = threadIdx.x;
    __shared__ unsigned h[BINS];
    __shared__ float    s[BINS];
    __shared__ unsigned csum[THREADS];
    __shared__ double   dred[THREADS];
    __shared__ unsigned sh_b1, sh_rem1;
    for (int i = t; i < BINS; i += THREADS) {
        h[i] = gcnt[row * BINS + i];
        s[i] = gsum[row * BINS + i];
    }
    __syncthreads();

    unsigned cs = 0;
#pragma unroll
    for (int j = 0; j < 8; ++j) cs += h[t * 8 + j];
    csum[t] = cs;
    __syncthreads();
    // suffix scan: csum[t] = count over bins [t*8 .. 2047]
    for (int off = 1; off < THREADS; off <<= 1) {
        unsigned add = (t + off < THREADS) ? csum[t + off] : 0;
        __syncthreads();
        csum[t] += add;
        __syncthreads();
    }
    unsigned suffIncl = csum[t];
    unsigned suffExcl = (t + 1 < THREADS) ? csum[t + 1] : 0;
    if (suffExcl < K_SEL && suffIncl >= K_SEL) {
        unsigned cum = suffExcl;
        for (int j = 7; j >= 0; --j) {
            unsigned c = h[t * 8 + j];
            if (cum + c >= K_SEL) {
                sh_b1 = (unsigned)(t * 8 + j);
                sh_rem1 = K_SEL - cum;
                break;
            }
            cum += c;
        }
    }
    __syncthreads();
    unsigned b1 = sh_b1;
    unsigned rem1 = sh_rem1;

    // exact sum of all bins strictly above b1
    double ds = 0.0;
#pragma unroll
    for (int j = 0; j < 8; ++j) {
        int bin = t * 8 + j;
        if (bin > (int)b1) ds += (double)s[bin];
    }
    dred[t] = ds;
    __syncthreads();
    for (int off = THREADS / 2; off > 0; off >>= 1) {
        if (t < off) dred[t] += dred[t + off];
        __syncthreads();
    }
    if (t == 0) {
        double center = ((double)b1 + 0.5) * (1.0 / 256.0);
        rowtot[row] = dred[0] + (double)rem1 * center;
    }
}

// ---------- Output: mean over all rows' top-k ----------
__global__ void k_out(const double* __restrict__ rowtot, float* __restrict__ out) {
    double acc = 0.0;
    for (int i = 0; i < ROWS; ++i) acc += rowtot[i];
    out[0] = (float)(acc / ((double)ROWS * (double)K_SEL));
}

extern "C" void kernel_launch(void* const* d_in, const int* in_sizes, int n_in,
                              void* d_out, int out_size, void* d_ws, size_t ws_size,
                              hipStream_t stream) {
    const float4* lg = (const float4*)d_in[0];
    const float4* tg = (const float4*)d_in[1];
    float* out = (float*)d_out;
    (void)in_sizes; (void)n_in; (void)out_size; (void)ws_size;

    // workspace layout
    char* ws = (char*)d_ws;
    unsigned* gcnt   = (unsigned*)(ws);                  // 64*2048*4 = 524288
    float*    gsum   = (float*)   (ws + 524288);         // 524288
    double*   rowtot = (double*)  (ws + 1048576);        // 512
    size_t small_bytes = 1049088;

    (void)hipMemsetAsync(d_ws, 0, small_bytes, stream);

    k_main<<<ROWS * 32, THREADS, 0, stream>>>(lg, tg, gcnt, gsum);
    k_finalize<<<ROWS, THREADS, 0, stream>>>(gcnt, gsum, rowtot);
    k_out<<<1, 1, 0, stream>>>(rowtot, out);
}

// Round 6
// 46.247 us; speedup vs baseline: 2.3309x; 2.3309x over previous
//
#include <hip/hip_runtime.h>

// B=16, C=4, H=512, W=512 ; rows=64 ; row length=262144 ; k=26214
// answer = sum(topk loss per row) / (64*26214)
//
// Threshold-based top-k sum: f(T) = sum_{l>T} l + (k - N(T))*T has f'(T)=k-N(T),
// which vanishes at the true k-th value => second-order accurate in T error.
// T is estimated per row from a 1/16 sample histogram; the full pass is a pure
// streaming compare+accumulate with NO LDS atomics (hot-bin serialization killed
// rounds 4/5: loss pdf has a log-singularity at log(2), ~2% of mass in one bin).

#define ROWS 64
#define ROW_N4 65536            // float4 per row
#define K_SEL 26214u
#define THREADS 256
#define BINS 2048               // linear bins over [0,8), width 1/256
#define NSUB 4
#define CHUNK4 2048             // float4 per k_pass block

// fast BCE-with-logits: max(x,0) - x*y + log1p(exp(-|x|))
__device__ __forceinline__ float loss_fast(float x, float y) {
    float a = fabsf(x);
    float t = __builtin_amdgcn_exp2f(a * -1.44269504088896f);       // e^-a
    float sp = 0.69314718055995f * __builtin_amdgcn_logf(1.0f + t); // ln2*log2(1+t)
    return fmaxf(x, 0.0f) - x * y + sp;
}
__device__ __forceinline__ unsigned bin_of(float l) {
    unsigned b = (unsigned)(l * 256.0f);
    return b > (BINS - 1u) ? (BINS - 1u) : b;
}

// ---------- Phase A: sampled per-row histogram (counts only) ----------
// 4 blocks per row; each block: 256 threads x 4 float4 = 4096 float4/row total = 1/16 of row,
// taken as 16 evenly-spaced 1KB stripes (data iid -> unbiased).
__global__ __launch_bounds__(THREADS)
void k_sample(const float4* __restrict__ lg, const float4* __restrict__ tg,
              unsigned* __restrict__ gcnt) {
    __shared__ unsigned h[BINS * NSUB];          // 32 KB
    int t = threadIdx.x;
    for (int i = t; i < BINS * NSUB; i += THREADS) h[i] = 0;
    __syncthreads();

    int row = blockIdx.x >> 2;
    int s = blockIdx.x & 3;
    int sub = t & (NSUB - 1);

#pragma unroll
    for (int i = 0; i < 4; ++i) {
        int m = s * 4 + i;                        // stripe 0..15
        int idx = row * ROW_N4 + m * 4096 + t;
        float4 x = lg[idx];
        float4 y = tg[idx];
        atomicAdd(&h[bin_of(loss_fast(x.x, y.x)) * NSUB + sub], 1u);
        atomicAdd(&h[bin_of(loss_fast(x.y, y.y)) * NSUB + sub], 1u);
        atomicAdd(&h[bin_of(loss_fast(x.z, y.z)) * NSUB + sub], 1u);
        atomicAdd(&h[bin_of(loss_fast(x.w, y.w)) * NSUB + sub], 1u);
    }
    __syncthreads();
    unsigned* gc = gcnt + row * BINS;
    const uint4* h4 = (const uint4*)h;
    for (int i = t; i < BINS; i += THREADS) {
        uint4 v = h4[i];
        unsigned c = v.x + v.y + v.z + v.w;
        if (c) atomicAdd(&gc[i], c);
    }
}

// ---------- Select per-row threshold T from sample histogram ----------
// Sample has 16384 elements; target quantile count = K_SEL/16 = 1638.
__global__ __launch_bounds__(THREADS)
void k_sel(const unsigned* __restrict__ gcnt, float* __restrict__ Trow) {
    const unsigned target = 1638u;
    int row = blockIdx.x;
    int t = threadIdx.x;
    __shared__ unsigned h[BINS];
    __shared__ unsigned csum[THREADS];
    for (int i = t; i < BINS; i += THREADS) h[i] = gcnt[row * BINS + i];
    __syncthreads();

    unsigned s = 0;
#pragma unroll
    for (int j = 0; j < 8; ++j) s += h[t * 8 + j];
    csum[t] = s;
    __syncthreads();
    for (int off = 1; off < THREADS; off <<= 1) {
        unsigned add = (t + off < THREADS) ? csum[t + off] : 0;
        __syncthreads();
        csum[t] += add;
        __syncthreads();
    }
    unsigned suffIncl = csum[t];
    unsigned suffExcl = (t + 1 < THREADS) ? csum[t + 1] : 0;
    if (suffExcl < target && suffIncl >= target) {
        unsigned cum = suffExcl;
        for (int j = 7; j >= 0; --j) {
            unsigned c = h[t * 8 + j];
            if (cum + c >= target) {
                Trow[row] = ((float)(t * 8 + j) + 0.5f) * (1.0f / 256.0f);
                break;
            }
            cum += c;
        }
    }
}

// ---------- Full pass: stream, compare to T, accumulate in registers ----------
__global__ __launch_bounds__(THREADS)
void k_pass(const float4* __restrict__ lg, const float4* __restrict__ tg,
            const float* __restrict__ Trow,
            double* __restrict__ rowsum, unsigned* __restrict__ rowcnt) {
    __shared__ float red_s[THREADS];
    __shared__ unsigned red_c[THREADS];
    int t = threadIdx.x;
    int row = blockIdx.x >> 5;
    int chunk = blockIdx.x & 31;
    int base = row * ROW_N4 + chunk * CHUNK4;
    float T = Trow[row];

    float lsum = 0.0f;
    unsigned lcnt = 0;
#pragma unroll
    for (int j = 0; j < 8; ++j) {
        int idx = base + j * THREADS + t;
        float4 x = lg[idx];
        float4 y = tg[idx];
        float l0 = loss_fast(x.x, y.x);
        float l1 = loss_fast(x.y, y.y);
        float l2 = loss_fast(x.z, y.z);
        float l3 = loss_fast(x.w, y.w);
        if (l0 > T) { lsum += l0; ++lcnt; }
        if (l1 > T) { lsum += l1; ++lcnt; }
        if (l2 > T) { lsum += l2; ++lcnt; }
        if (l3 > T) { lsum += l3; ++lcnt; }
    }
    red_s[t] = lsum;
    red_c[t] = lcnt;
    __syncthreads();
    for (int off = THREADS / 2; off > 0; off >>= 1) {
        if (t < off) { red_s[t] += red_s[t + off]; red_c[t] += red_c[t + off]; }
        __syncthreads();
    }
    if (t == 0) {
        atomicAdd(&rowsum[row], (double)red_s[0]);
        atomicAdd(&rowcnt[row], red_c[0]);
    }
}

// ---------- Finalize: rowtot = sum_above + (k - N)*T ; mean over rows ----------
__global__ __launch_bounds__(ROWS)
void k_finalize(const double* __restrict__ rowsum, const unsigned* __restrict__ rowcnt,
                const float* __restrict__ Trow, float* __restrict__ out) {
    __shared__ double tot[ROWS];
    int r = threadIdx.x;
    double T = (double)Trow[r];
    double corr = ((double)(int)K_SEL - (double)(int)rowcnt[r]) * T;
    tot[r] = rowsum[r] + corr;
    __syncthreads();
    if (r == 0) {
        double s = 0.0;
        for (int i = 0; i < ROWS; ++i) s += tot[i];
        out[0] = (float)(s / ((double)ROWS * (double)K_SEL));
    }
}

extern "C" void kernel_launch(void* const* d_in, const int* in_sizes, int n_in,
                              void* d_out, int out_size, void* d_ws, size_t ws_size,
                              hipStream_t stream) {
    const float4* lg = (const float4*)d_in[0];
    const float4* tg = (const float4*)d_in[1];
    float* out = (float*)d_out;
    (void)in_sizes; (void)n_in; (void)out_size; (void)ws_size;

    // workspace layout
    char* ws = (char*)d_ws;
    unsigned* gcnt   = (unsigned*)(ws);                  // 64*2048*4 = 524288
    float*    Trow   = (float*)   (ws + 524288);         // 256
    double*   rowsum = (double*)  (ws + 524544);         // 512 (8-aligned)
    unsigned* rowcnt = (unsigned*)(ws + 525056);         // 256
    size_t small_bytes = 525312;

    (void)hipMemsetAsync(d_ws, 0, small_bytes, stream);

    k_sample<<<ROWS * 4, THREADS, 0, stream>>>(lg, tg, gcnt);
    k_sel<<<ROWS, THREADS, 0, stream>>>(gcnt, Trow);
    k_pass<<<ROWS * 32, THREADS, 0, stream>>>(lg, tg, Trow, rowsum, rowcnt);
    k_finalize<<<1, ROWS, 0, stream>>>(rowsum, rowcnt, Trow, out);
}

// Round 7
// 45.169 us; speedup vs baseline: 2.3865x; 1.0239x over previous
//
#include <hip/hip_runtime.h>

// B=16, C=4, H=512, W=512 ; rows=64 ; row length=262144 ; k=26214
// answer = sum(topk loss per row) / (64*26214)
//
// Threshold-based top-k sum: f(T) = sum_{l>T} l + (k - N(T))*T has f'(T)=k-N(T),
// which vanishes at the true k-th value => second-order accurate in T error.
// T estimated per row from a 1/16 sample histogram; full pass is a pure stream
// with all 16 loads per thread issued before compute (MLP fix for round-6's
// latency-bound k_pass: VGPR=24 showed only one pair in flight).

#define ROWS 64
#define ROW_N4 65536            // float4 per row
#define K_SEL 26214u
#define THREADS 256
#define BINS 2048               // linear bins over [0,8), width 1/256
#define NSUB 4
#define CHUNK4 2048             // float4 per k_pass block

// fast BCE-with-logits: max(x,0) - x*y + log1p(exp(-|x|))
__device__ __forceinline__ float loss_fast(float x, float y) {
    float a = fabsf(x);
    float t = __builtin_amdgcn_exp2f(a * -1.44269504088896f);       // e^-a
    float sp = 0.69314718055995f * __builtin_amdgcn_logf(1.0f + t); // ln2*log2(1+t)
    return fmaxf(x, 0.0f) - x * y + sp;
}
__device__ __forceinline__ unsigned bin_of(float l) {
    unsigned b = (unsigned)(l * 256.0f);
    return b > (BINS - 1u) ? (BINS - 1u) : b;
}

// ---------- Phase A: sampled per-row histogram (counts only, 1/16 of data) ----------
__global__ __launch_bounds__(THREADS)
void k_sample(const float4* __restrict__ lg, const float4* __restrict__ tg,
              unsigned* __restrict__ gcnt) {
    __shared__ unsigned h[BINS * NSUB];          // 32 KB
    int t = threadIdx.x;
    for (int i = t; i < BINS * NSUB; i += THREADS) h[i] = 0;
    __syncthreads();

    int row = blockIdx.x >> 2;
    int s = blockIdx.x & 3;
    int sub = t & (NSUB - 1);

    // batch the 4 stripe loads before histogramming (same MLP fix)
    float4 xs[4], ys[4];
#pragma unroll
    for (int i = 0; i < 4; ++i) {
        int idx = row * ROW_N4 + (s * 4 + i) * 4096 + t;
        xs[i] = lg[idx];
        ys[i] = tg[idx];
    }
#pragma unroll
    for (int i = 0; i < 4; ++i) {
        atomicAdd(&h[bin_of(loss_fast(xs[i].x, ys[i].x)) * NSUB + sub], 1u);
        atomicAdd(&h[bin_of(loss_fast(xs[i].y, ys[i].y)) * NSUB + sub], 1u);
        atomicAdd(&h[bin_of(loss_fast(xs[i].z, ys[i].z)) * NSUB + sub], 1u);
        atomicAdd(&h[bin_of(loss_fast(xs[i].w, ys[i].w)) * NSUB + sub], 1u);
    }
    __syncthreads();
    unsigned* gc = gcnt + row * BINS;
    const uint4* h4 = (const uint4*)h;
    for (int i = t; i < BINS; i += THREADS) {
        uint4 v = h4[i];
        unsigned c = v.x + v.y + v.z + v.w;
        if (c) atomicAdd(&gc[i], c);
    }
}

// ---------- Select per-row threshold T (sample quantile: 26214/16 = 1638) ----------
__global__ __launch_bounds__(THREADS)
void k_sel(const unsigned* __restrict__ gcnt, float* __restrict__ Trow) {
    const unsigned target = 1638u;
    int row = blockIdx.x;
    int t = threadIdx.x;
    __shared__ unsigned h[BINS];
    __shared__ unsigned csum[THREADS];
    for (int i = t; i < BINS; i += THREADS) h[i] = gcnt[row * BINS + i];
    __syncthreads();

    unsigned s = 0;
#pragma unroll
    for (int j = 0; j < 8; ++j) s += h[t * 8 + j];
    csum[t] = s;
    __syncthreads();
    for (int off = 1; off < THREADS; off <<= 1) {
        unsigned add = (t + off < THREADS) ? csum[t + off] : 0;
        __syncthreads();
        csum[t] += add;
        __syncthreads();
    }
    unsigned suffIncl = csum[t];
    unsigned suffExcl = (t + 1 < THREADS) ? csum[t + 1] : 0;
    if (suffExcl < target && suffIncl >= target) {
        unsigned cum = suffExcl;
        for (int j = 7; j >= 0; --j) {
            unsigned c = h[t * 8 + j];
            if (cum + c >= target) {
                Trow[row] = ((float)(t * 8 + j) + 0.5f) * (1.0f / 256.0f);
                break;
            }
            cum += c;
        }
    }
}

// ---------- Full pass: 16 loads in flight, then compare+accumulate in registers ----------
__global__ __launch_bounds__(THREADS)
void k_pass(const float4* __restrict__ lg, const float4* __restrict__ tg,
            const float* __restrict__ Trow,
            double* __restrict__ rowsum, unsigned* __restrict__ rowcnt) {
    __shared__ float red_s[THREADS];
    __shared__ unsigned red_c[THREADS];
    int t = threadIdx.x;
    int row = blockIdx.x >> 5;
    int chunk = blockIdx.x & 31;
    int base = row * ROW_N4 + chunk * CHUNK4;
    float T = Trow[row];

    float4 xs[8], ys[8];
#pragma unroll
    for (int j = 0; j < 8; ++j) {
        int idx = base + j * THREADS + t;
        xs[j] = lg[idx];
        ys[j] = tg[idx];
    }

    float lsum = 0.0f;
    unsigned lcnt = 0;
#pragma unroll
    for (int j = 0; j < 8; ++j) {
        float l0 = loss_fast(xs[j].x, ys[j].x);
        float l1 = loss_fast(xs[j].y, ys[j].y);
        float l2 = loss_fast(xs[j].z, ys[j].z);
        float l3 = loss_fast(xs[j].w, ys[j].w);
        if (l0 > T) { lsum += l0; ++lcnt; }
        if (l1 > T) { lsum += l1; ++lcnt; }
        if (l2 > T) { lsum += l2; ++lcnt; }
        if (l3 > T) { lsum += l3; ++lcnt; }
    }
    red_s[t] = lsum;
    red_c[t] = lcnt;
    __syncthreads();
    for (int off = THREADS / 2; off > 0; off >>= 1) {
        if (t < off) { red_s[t] += red_s[t + off]; red_c[t] += red_c[t + off]; }
        __syncthreads();
    }
    if (t == 0) {
        atomicAdd(&rowsum[row], (double)red_s[0]);
        atomicAdd(&rowcnt[row], red_c[0]);
    }
}

// ---------- Finalize: rowtot = sum_above + (k - N)*T ; mean over rows ----------
__global__ __launch_bounds__(ROWS)
void k_finalize(const double* __restrict__ rowsum, const unsigned* __restrict__ rowcnt,
                const float* __restrict__ Trow, float* __restrict__ out) {
    __shared__ double tot[ROWS];
    int r = threadIdx.x;
    double T = (double)Trow[r];
    double corr = ((double)(int)K_SEL - (double)(int)rowcnt[r]) * T;
    tot[r] = rowsum[r] + corr;
    __syncthreads();
    if (r == 0) {
        double s = 0.0;
        for (int i = 0; i < ROWS; ++i) s += tot[i];
        out[0] = (float)(s / ((double)ROWS * (double)K_SEL));
    }
}

extern "C" void kernel_launch(void* const* d_in, const int* in_sizes, int n_in,
                              void* d_out, int out_size, void* d_ws, size_t ws_size,
                              hipStream_t stream) {
    const float4* lg = (const float4*)d_in[0];
    const float4* tg = (const float4*)d_in[1];
    float* out = (float*)d_out;
    (void)in_sizes; (void)n_in; (void)out_size; (void)ws_size;

    // workspace layout
    char* ws = (char*)d_ws;
    unsigned* gcnt   = (unsigned*)(ws);                  // 64*2048*4 = 524288
    float*    Trow   = (float*)   (ws + 524288);         // 256
    double*   rowsum = (double*)  (ws + 524544);         // 512 (8-aligned)
    unsigned* rowcnt = (unsigned*)(ws + 525056);         // 256
    size_t small_bytes = 525312;

    (void)hipMemsetAsync(d_ws, 0, small_bytes, stream);

    k_sample<<<ROWS * 4, THREADS, 0, stream>>>(lg, tg, gcnt);
    k_sel<<<ROWS, THREADS, 0, stream>>>(gcnt, Trow);
    k_pass<<<ROWS * 32, THREADS, 0, stream>>>(lg, tg, Trow, rowsum, rowcnt);
    k_finalize<<<1, ROWS, 0, stream>>>(rowsum, rowcnt, Trow, out);
}

// Round 8
// 44.138 us; speedup vs baseline: 2.4422x; 1.0234x over previous
//
#include <hip/hip_runtime.h>

// B=16, C=4, H=512, W=512 ; rows=64 ; row length=262144 ; k=26214
// answer = sum(topk loss per row) / (64*26214)
//
// Threshold-based top-k sum: f(T) = sum_{l>T} l + (k - N(T))*T has f'(T)=k-N(T)=0
// at the true k-th value => second-order accurate in T error.
// T estimated per row from a 1/16 sample histogram; full pass is a pure stream.
// Round-7 lesson: compiler sank the batched loads (VGPR stayed 36). Fix: pin all
// 16 global_load_dwordx4 ABOVE compute with sched_barrier(0) -> 512 B/wave in flight.

#define ROWS 64
#define ROW_N4 65536            // float4 per row
#define K_SEL 26214u
#define THREADS 256
#define BINS 2048               // linear bins over [0,8), width 1/256
#define NSUB 4
#define CHUNK4 2048             // float4 per k_pass block

// fast BCE-with-logits: max(x,0) - x*y + log1p(exp(-|x|))
__device__ __forceinline__ float loss_fast(float x, float y) {
    float a = fabsf(x);
    float t = __builtin_amdgcn_exp2f(a * -1.44269504088896f);       // e^-a
    float sp = 0.69314718055995f * __builtin_amdgcn_logf(1.0f + t); // ln2*log2(1+t)
    return fmaxf(x, 0.0f) - x * y + sp;
}
__device__ __forceinline__ unsigned bin_of(float l) {
    unsigned b = (unsigned)(l * 256.0f);
    return b > (BINS - 1u) ? (BINS - 1u) : b;
}

// ---------- Phase A: sampled per-row histogram (counts only, 1/16 of data) ----------
__global__ __launch_bounds__(THREADS)
void k_sample(const float4* __restrict__ lg, const float4* __restrict__ tg,
              unsigned* __restrict__ gcnt) {
    __shared__ unsigned h[BINS * NSUB];          // 32 KB
    int t = threadIdx.x;
    for (int i = t; i < BINS * NSUB; i += THREADS) h[i] = 0;
    __syncthreads();

    int row = blockIdx.x >> 2;
    int s = blockIdx.x & 3;
    int sub = t & (NSUB - 1);

    float4 xs[4], ys[4];
#pragma unroll
    for (int i = 0; i < 4; ++i) {
        int idx = row * ROW_N4 + (s * 4 + i) * 4096 + t;
        xs[i] = lg[idx];
        ys[i] = tg[idx];
    }
    __builtin_amdgcn_sched_barrier(0);   // keep all 8 loads issued before compute
#pragma unroll
    for (int i = 0; i < 4; ++i) {
        atomicAdd(&h[bin_of(loss_fast(xs[i].x, ys[i].x)) * NSUB + sub], 1u);
        atomicAdd(&h[bin_of(loss_fast(xs[i].y, ys[i].y)) * NSUB + sub], 1u);
        atomicAdd(&h[bin_of(loss_fast(xs[i].z, ys[i].z)) * NSUB + sub], 1u);
        atomicAdd(&h[bin_of(loss_fast(xs[i].w, ys[i].w)) * NSUB + sub], 1u);
    }
    __syncthreads();
    unsigned* gc = gcnt + row * BINS;
    const uint4* h4 = (const uint4*)h;
    for (int i = t; i < BINS; i += THREADS) {
        uint4 v = h4[i];
        unsigned c = v.x + v.y + v.z + v.w;
        if (c) atomicAdd(&gc[i], c);
    }
}

// ---------- Select per-row threshold T (sample quantile: 26214/16 = 1638) ----------
__global__ __launch_bounds__(THREADS)
void k_sel(const unsigned* __restrict__ gcnt, float* __restrict__ Trow) {
    const unsigned target = 1638u;
    int row = blockIdx.x;
    int t = threadIdx.x;
    __shared__ unsigned h[BINS];
    __shared__ unsigned csum[THREADS];
    for (int i = t; i < BINS; i += THREADS) h[i] = gcnt[row * BINS + i];
    __syncthreads();

    unsigned s = 0;
#pragma unroll
    for (int j = 0; j < 8; ++j) s += h[t * 8 + j];
    csum[t] = s;
    __syncthreads();
    for (int off = 1; off < THREADS; off <<= 1) {
        unsigned add = (t + off < THREADS) ? csum[t + off] : 0;
        __syncthreads();
        csum[t] += add;
        __syncthreads();
    }
    unsigned suffIncl = csum[t];
    unsigned suffExcl = (t + 1 < THREADS) ? csum[t + 1] : 0;
    if (suffExcl < target && suffIncl >= target) {
        unsigned cum = suffExcl;
        for (int j = 7; j >= 0; --j) {
            unsigned c = h[t * 8 + j];
            if (cum + c >= target) {
                Trow[row] = ((float)(t * 8 + j) + 0.5f) * (1.0f / 256.0f);
                break;
            }
            cum += c;
        }
    }
}

// ---------- Full pass: 16 loads pinned in flight, then compare+accumulate ----------
__global__ __launch_bounds__(THREADS)
void k_pass(const float4* __restrict__ lg, const float4* __restrict__ tg,
            const float* __restrict__ Trow,
            double* __restrict__ rowsum, unsigned* __restrict__ rowcnt) {
    __shared__ float red_s[THREADS];
    __shared__ unsigned red_c[THREADS];
    int t = threadIdx.x;
    int row = blockIdx.x >> 5;
    int chunk = blockIdx.x & 31;
    int base = row * ROW_N4 + chunk * CHUNK4;
    float T = Trow[row];

    float4 xs[8], ys[8];
#pragma unroll
    for (int j = 0; j < 8; ++j) {
        int idx = base + j * THREADS + t;
        xs[j] = lg[idx];
        ys[j] = tg[idx];
    }
    __builtin_amdgcn_sched_barrier(0);   // forbid sinking any load below this point

    float lsum = 0.0f;
    unsigned lcnt = 0;
#pragma unroll
    for (int j = 0; j < 8; ++j) {
        float l0 = loss_fast(xs[j].x, ys[j].x);
        float l1 = loss_fast(xs[j].y, ys[j].y);
        float l2 = loss_fast(xs[j].z, ys[j].z);
        float l3 = loss_fast(xs[j].w, ys[j].w);
        if (l0 > T) { lsum += l0; ++lcnt; }
        if (l1 > T) { lsum += l1; ++lcnt; }
        if (l2 > T) { lsum += l2; ++lcnt; }
        if (l3 > T) { lsum += l3; ++lcnt; }
    }
    red_s[t] = lsum;
    red_c[t] = lcnt;
    __syncthreads();
    for (int off = THREADS / 2; off > 0; off >>= 1) {
        if (t < off) { red_s[t] += red_s[t + off]; red_c[t] += red_c[t + off]; }
        __syncthreads();
    }
    if (t == 0) {
        atomicAdd(&rowsum[row], (double)red_s[0]);
        atomicAdd(&rowcnt[row], red_c[0]);
    }
}

// ---------- Finalize: rowtot = sum_above + (k - N)*T ; mean over rows ----------
__global__ __launch_bounds__(ROWS)
void k_finalize(const double* __restrict__ rowsum, const unsigned* __restrict__ rowcnt,
                const float* __restrict__ Trow, float* __restrict__ out) {
    __shared__ double tot[ROWS];
    int r = threadIdx.x;
    double T = (double)Trow[r];
    double corr = ((double)(int)K_SEL - (double)(int)rowcnt[r]) * T;
    tot[r] = rowsum[r] + corr;
    __syncthreads();
    if (r == 0) {
        double s = 0.0;
        for (int i = 0; i < ROWS; ++i) s += tot[i];
        out[0] = (float)(s / ((double)ROWS * (double)K_SEL));
    }
}

extern "C" void kernel_launch(void* const* d_in, const int* in_sizes, int n_in,
                              void* d_out, int out_size, void* d_ws, size_t ws_size,
                              hipStream_t stream) {
    const float4* lg = (const float4*)d_in[0];
    const float4* tg = (const float4*)d_in[1];
    float* out = (float*)d_out;
    (void)in_sizes; (void)n_in; (void)out_size; (void)ws_size;

    // workspace layout
    char* ws = (char*)d_ws;
    unsigned* gcnt   = (unsigned*)(ws);                  // 64*2048*4 = 524288
    float*    Trow   = (float*)   (ws + 524288);         // 256
    double*   rowsum = (double*)  (ws + 524544);         // 512 (8-aligned)
    unsigned* rowcnt = (unsigned*)(ws + 525056);         // 256
    size_t small_bytes = 525312;

    (void)hipMemsetAsync(d_ws, 0, small_bytes, stream);

    k_sample<<<ROWS * 4, THREADS, 0, stream>>>(lg, tg, gcnt);
    k_sel<<<ROWS, THREADS, 0, stream>>>(gcnt, Trow);
    k_pass<<<ROWS * 32, THREADS, 0, stream>>>(lg, tg, Trow, rowsum, rowcnt);
    k_finalize<<<1, ROWS, 0, stream>>>(rowsum, rowcnt, Trow, out);
}